// Round 3
// baseline (317.706 us; speedup 1.0000x reference)
//
#include <hip/hip_runtime.h>
#include <hip/hip_bf16.h>

#define NEG 0.2f

__device__ __forceinline__ float leaky(float x){ return x > 0.f ? x : NEG*x; }
__device__ __forceinline__ float sel4(float4 q, int head){
  float lo = (head & 1) ? q.y : q.x;
  float hi = (head & 1) ? q.w : q.z;
  return (head & 2) ? hi : lo;
}
__device__ __forceinline__ float b2f_lo(unsigned u){ return __uint_as_float(u << 16); }
__device__ __forceinline__ float b2f_hi(unsigned u){ return __uint_as_float(u & 0xffff0000u); }
__device__ __forceinline__ unsigned short f2b(float f){
  __hip_bfloat16 b = __float2bfloat16(f);
  return *(unsigned short*)&b;
}

// ---------------- K1: hf16 = bf16(h @ fcw^T), fused el/er. h read ONCE. ----------------
// grid.x = ceil(N/64). 256 threads. Both 64-feat halves computed per block.
__global__ __launch_bounds__(256) void k_proj(
    const float* __restrict__ h, const float* __restrict__ fcw,
    const float* __restrict__ attn_l, const float* __restrict__ attn_r,
    unsigned short* __restrict__ hf16, float* __restrict__ el, float* __restrict__ er, int N)
{
  __shared__ float fcs[64][128];
  __shared__ float hs[4][16][128];
  const int tid = threadIdx.x;
  const int wave = tid >> 6, lane = tid & 63;
  const int fq = lane & 15, ng = lane >> 4;
  const int nb0 = blockIdx.x*64 + wave*16;

  // stage this wave's 16 h rows (once)
  for (int t = lane; t < 16*32; t += 64) {
    int n = t >> 5, c = t & 31;
    int gn = nb0 + n; if (gn >= N) gn = N-1;
    *(float4*)&hs[wave][n][4*c] = *(const float4*)&h[(size_t)gn*128 + 4*c];
  }

  for (int g = 0; g < 2; ++g) {
    if (g) __syncthreads();           // protect fcs before restage
    // stage fc rows g*64 .. g*64+63, swizzle k-quads by (row>>2)&7
    for (int i = tid; i < 64*32; i += 256) {
      int f = i >> 5, q = i & 31;
      float4 w = *(const float4*)&fcw[(size_t)(g*64 + f)*128 + 4*q];
      *(float4*)&fcs[f][4*(q ^ ((f>>2)&7))] = w;
    }
    __syncthreads();

    float acc[4][4];
    #pragma unroll
    for (int j = 0; j < 4; ++j)
      #pragma unroll
      for (int i = 0; i < 4; ++i) acc[j][i] = 0.f;

    #pragma unroll 8
    for (int kk = 0; kk < 32; ++kk) {
      const int qc = 4*(kk ^ (fq & 7));
      float4 r0 = *(const float4*)&fcs[4*fq + 0][qc];
      float4 r1 = *(const float4*)&fcs[4*fq + 1][qc];
      float4 r2 = *(const float4*)&fcs[4*fq + 2][qc];
      float4 r3 = *(const float4*)&fcs[4*fq + 3][qc];
      #pragma unroll
      for (int j = 0; j < 4; ++j) {
        float4 hv = *(const float4*)&hs[wave][ng*4 + j][4*kk];
        acc[j][0] += hv.x*r0.x + hv.y*r0.y + hv.z*r0.z + hv.w*r0.w;
        acc[j][1] += hv.x*r1.x + hv.y*r1.y + hv.z*r1.z + hv.w*r1.w;
        acc[j][2] += hv.x*r2.x + hv.y*r2.y + hv.z*r2.z + hv.w*r2.w;
        acc[j][3] += hv.x*r3.x + hv.y*r3.y + hv.z*r3.z + hv.w*r3.w;
      }
    }

    const float4 al4 = *(const float4*)&attn_l[g*64 + 4*fq];
    const float4 ar4 = *(const float4*)&attn_r[g*64 + 4*fq];
    #pragma unroll
    for (int j = 0; j < 4; ++j) {
      int gn = nb0 + ng*4 + j;
      float4 o = make_float4(acc[j][0], acc[j][1], acc[j][2], acc[j][3]);
      float elp = o.x*al4.x + o.y*al4.y + o.z*al4.z + o.w*al4.w;
      float erp = o.x*ar4.x + o.y*ar4.y + o.z*ar4.z + o.w*ar4.w;
      elp += __shfl_xor(elp, 1); elp += __shfl_xor(elp, 2); elp += __shfl_xor(elp, 4);
      erp += __shfl_xor(erp, 1); erp += __shfl_xor(erp, 2); erp += __shfl_xor(erp, 4);
      if (gn < N) {
        ushort4 ob;
        ob.x = f2b(o.x); ob.y = f2b(o.y); ob.z = f2b(o.z); ob.w = f2b(o.w);
        *(ushort4*)&hf16[(size_t)gn*128 + g*64 + 4*fq] = ob;
        if ((lane & 7) == 0) {
          int head = g*2 + ((lane >> 3) & 1);
          el[(size_t)gn*4 + head] = elp;
          er[(size_t)gn*4 + head] = erp;
        }
      }
    }
  }
}

// ---------------- CSR build ----------------
__global__ void k_hist(const int* __restrict__ dst, int* __restrict__ counts, int E) {
  int e = (blockIdx.x*256 + threadIdx.x)*4;
  if (e + 3 < E) {
    int4 d = *(const int4*)&dst[e];
    atomicAdd(&counts[d.x], 1); atomicAdd(&counts[d.y], 1);
    atomicAdd(&counts[d.z], 1); atomicAdd(&counts[d.w], 1);
  } else {
    for (int k = e; k < E; ++k) atomicAdd(&counts[dst[k]], 1);
  }
}

// single-block scan: offsets = exclusive_scan(counts); cursor = offsets
__global__ __launch_bounds__(1024) void k_scan(const int* __restrict__ counts, int N,
    int* __restrict__ offsets, int* __restrict__ cursor) {
  __shared__ int part[1024];
  const int t = threadIdx.x;
  const int C = (N + 1023) / 1024;
  const int base = t * C;
  int s = 0;
  for (int k = 0; k < C; ++k) {
    int i = base + k;
    if (i < N) s += counts[i];
  }
  part[t] = s;
  __syncthreads();
  for (int off = 1; off < 1024; off <<= 1) {
    int x = (t >= off) ? part[t - off] : 0;
    __syncthreads();
    part[t] += x;
    __syncthreads();
  }
  int run = part[t] - s;   // exclusive prefix
  for (int k = 0; k < C; ++k) {
    int i = base + k;
    if (i < N) {
      int c = counts[i];
      offsets[i] = run;
      cursor[i]  = run;
      run += c;
    }
  }
}

__global__ void k_scatter(const int* __restrict__ dst, const int* __restrict__ src,
                          int* __restrict__ cursor, int2* __restrict__ epack, int E) {
  int e = (blockIdx.x*256 + threadIdx.x)*4;
  if (e + 3 < E) {
    int4 d = *(const int4*)&dst[e];
    int4 s = *(const int4*)&src[e];
    int p0 = atomicAdd(&cursor[d.x], 1); epack[p0] = make_int2(e+0, s.x);
    int p1 = atomicAdd(&cursor[d.y], 1); epack[p1] = make_int2(e+1, s.y);
    int p2 = atomicAdd(&cursor[d.z], 1); epack[p2] = make_int2(e+2, s.z);
    int p3 = atomicAdd(&cursor[d.w], 1); epack[p3] = make_int2(e+3, s.w);
  } else {
    for (int k = e; k < E; ++k) {
      int d = dst[k];
      int p = atomicAdd(&cursor[d], 1);
      epack[p] = make_int2(k, src[k]);
    }
  }
}

// ---------------- K2: per-dst softmax + aggregation (1 wave per node) ----------------
// pass A (lane-per-edge, deg<=64 fast path): compute max/sum, write a_out,
//   stash a and (e,src) in LDS.
// pass B: 8 edge groups x 8 lanes, lane owns 16 feats (bf16 hf gather).
__global__ __launch_bounds__(256) void k_aggr(
    const int2* __restrict__ epack, const int* __restrict__ offsets, const int* __restrict__ counts,
    const unsigned short* __restrict__ hf16, const float* __restrict__ el, const float* __restrict__ er,
    float* __restrict__ out, float* __restrict__ a_out, int N)
{
  __shared__ float as[4][64][4];
  __shared__ int2  es[4][64];
  const int wave = threadIdx.x >> 6, lane = threadIdx.x & 63;
  const int v = blockIdx.x*4 + wave;
  if (v >= N) return;
  const int start = offsets[v];
  const int deg   = counts[v];
  const float4 er4 = *(const float4*)&er[(size_t)v*4];

  // ---- pass A ----
  const bool act = lane < deg;
  float4 e4 = make_float4(-1e30f, -1e30f, -1e30f, -1e30f);
  int2 myp = make_int2(0, 0);
  if (act) {
    myp = epack[start + lane];
    float4 el4 = *(const float4*)&el[(size_t)myp.y*4];
    e4.x = leaky(el4.x + er4.x);
    e4.y = leaky(el4.y + er4.y);
    e4.z = leaky(el4.z + er4.z);
    e4.w = leaky(el4.w + er4.w);
  }
  float4 m4 = e4;
  for (int j = lane + 64; j < deg; j += 64) {   // deg>64: essentially never
    int2 pr = epack[start + j];
    float4 el4 = *(const float4*)&el[(size_t)pr.y*4];
    m4.x = fmaxf(m4.x, leaky(el4.x + er4.x));
    m4.y = fmaxf(m4.y, leaky(el4.y + er4.y));
    m4.z = fmaxf(m4.z, leaky(el4.z + er4.z));
    m4.w = fmaxf(m4.w, leaky(el4.w + er4.w));
  }
  #pragma unroll
  for (int mm = 32; mm; mm >>= 1) {
    m4.x = fmaxf(m4.x, __shfl_xor(m4.x, mm));
    m4.y = fmaxf(m4.y, __shfl_xor(m4.y, mm));
    m4.z = fmaxf(m4.z, __shfl_xor(m4.z, mm));
    m4.w = fmaxf(m4.w, __shfl_xor(m4.w, mm));
  }
  float4 x4 = make_float4(0.f, 0.f, 0.f, 0.f);
  if (act) {
    x4.x = __expf(e4.x - m4.x);
    x4.y = __expf(e4.y - m4.y);
    x4.z = __expf(e4.z - m4.z);
    x4.w = __expf(e4.w - m4.w);
  }
  float4 s4 = x4;
  for (int j = lane + 64; j < deg; j += 64) {   // rare
    int2 pr = epack[start + j];
    float4 el4 = *(const float4*)&el[(size_t)pr.y*4];
    s4.x += __expf(leaky(el4.x + er4.x) - m4.x);
    s4.y += __expf(leaky(el4.y + er4.y) - m4.y);
    s4.z += __expf(leaky(el4.z + er4.z) - m4.z);
    s4.w += __expf(leaky(el4.w + er4.w) - m4.w);
  }
  #pragma unroll
  for (int mm = 32; mm; mm >>= 1) {
    s4.x += __shfl_xor(s4.x, mm);
    s4.y += __shfl_xor(s4.y, mm);
    s4.z += __shfl_xor(s4.z, mm);
    s4.w += __shfl_xor(s4.w, mm);
  }
  const float4 r4 = make_float4(1.f/s4.x, 1.f/s4.y, 1.f/s4.z, 1.f/s4.w);

  if (act) {
    float4 a4 = make_float4(x4.x*r4.x, x4.y*r4.y, x4.z*r4.z, x4.w*r4.w);
    *(float4*)&a_out[(size_t)myp.x*4] = a4;
    *(float4*)&as[wave][lane][0] = a4;
    es[wave][lane] = myp;
  }
  for (int j = lane + 64; j < deg; j += 64) {   // rare: a_out for spill edges
    int2 pr = epack[start + j];
    float4 el4 = *(const float4*)&el[(size_t)pr.y*4];
    float4 a4;
    a4.x = __expf(leaky(el4.x + er4.x) - m4.x) * r4.x;
    a4.y = __expf(leaky(el4.y + er4.y) - m4.y) * r4.y;
    a4.z = __expf(leaky(el4.z + er4.z) - m4.z) * r4.z;
    a4.w = __expf(leaky(el4.w + er4.w) - m4.w) * r4.w;
    *(float4*)&a_out[(size_t)pr.x*4] = a4;
  }

  // ---- pass B: aggregate, 8 edges in flight ----
  const int g = lane >> 3;      // edge slot 0..7
  const int l = lane & 7;       // feature sublane: feats 16l..16l+15
  const int head = l >> 1;
  float acc[16];
  #pragma unroll
  for (int k = 0; k < 16; ++k) acc[k] = 0.f;

  const int degL = deg < 64 ? deg : 64;
  for (int j = 0; j < degL; j += 8) {
    const int je = j + g;
    const bool valid = je < degL;
    const int jec = valid ? je : 0;
    int2 pr = es[wave][jec];
    float a = valid ? as[wave][jec][head] : 0.f;
    const unsigned short* hp = &hf16[(size_t)pr.y*128 + 16*l];
    uint4 q0 = *(const uint4*)hp;
    uint4 q1 = *(const uint4*)(hp + 8);
    acc[0]  += a*b2f_lo(q0.x); acc[1]  += a*b2f_hi(q0.x);
    acc[2]  += a*b2f_lo(q0.y); acc[3]  += a*b2f_hi(q0.y);
    acc[4]  += a*b2f_lo(q0.z); acc[5]  += a*b2f_hi(q0.z);
    acc[6]  += a*b2f_lo(q0.w); acc[7]  += a*b2f_hi(q0.w);
    acc[8]  += a*b2f_lo(q1.x); acc[9]  += a*b2f_hi(q1.x);
    acc[10] += a*b2f_lo(q1.y); acc[11] += a*b2f_hi(q1.y);
    acc[12] += a*b2f_lo(q1.z); acc[13] += a*b2f_hi(q1.z);
    acc[14] += a*b2f_lo(q1.w); acc[15] += a*b2f_hi(q1.w);
  }
  for (int j = 64; j < deg; j += 8) {   // deg>64 fallback: recompute a
    const int je = j + g;
    const bool valid = je < deg;
    int2 pr = epack[start + (valid ? je : 0)];
    float mh  = sel4(m4, head), rh = sel4(r4, head), erh = sel4(er4, head);
    float a = __expf(leaky(el[(size_t)pr.y*4 + head] + erh) - mh) * rh;
    if (!valid) a = 0.f;
    const unsigned short* hp = &hf16[(size_t)pr.y*128 + 16*l];
    uint4 q0 = *(const uint4*)hp;
    uint4 q1 = *(const uint4*)(hp + 8);
    acc[0]  += a*b2f_lo(q0.x); acc[1]  += a*b2f_hi(q0.x);
    acc[2]  += a*b2f_lo(q0.y); acc[3]  += a*b2f_hi(q0.y);
    acc[4]  += a*b2f_lo(q0.z); acc[5]  += a*b2f_hi(q0.z);
    acc[6]  += a*b2f_lo(q0.w); acc[7]  += a*b2f_hi(q0.w);
    acc[8]  += a*b2f_lo(q1.x); acc[9]  += a*b2f_hi(q1.x);
    acc[10] += a*b2f_lo(q1.y); acc[11] += a*b2f_hi(q1.y);
    acc[12] += a*b2f_lo(q1.z); acc[13] += a*b2f_hi(q1.z);
    acc[14] += a*b2f_lo(q1.w); acc[15] += a*b2f_hi(q1.w);
  }

  #pragma unroll
  for (int k = 0; k < 16; ++k) {
    acc[k] += __shfl_xor(acc[k], 8);
    acc[k] += __shfl_xor(acc[k], 16);
    acc[k] += __shfl_xor(acc[k], 32);
  }
  if (g == 0) {
    float* op = &out[(size_t)v*128 + 16*l];
    *(float4*)(op)      = make_float4(acc[0],  acc[1],  acc[2],  acc[3]);
    *(float4*)(op + 4)  = make_float4(acc[4],  acc[5],  acc[6],  acc[7]);
    *(float4*)(op + 8)  = make_float4(acc[8],  acc[9],  acc[10], acc[11]);
    *(float4*)(op + 12) = make_float4(acc[12], acc[13], acc[14], acc[15]);
  }
}

extern "C" void kernel_launch(void* const* d_in, const int* in_sizes, int n_in,
                              void* d_out, int out_size, void* d_ws, size_t ws_size,
                              hipStream_t stream) {
  const float* h      = (const float*)d_in[0];
  const float* fcw    = (const float*)d_in[1];
  const float* attn_l = (const float*)d_in[2];
  const float* attn_r = (const float*)d_in[3];
  const int*   src    = (const int*)d_in[4];
  const int*   dst    = (const int*)d_in[5];
  const int N = in_sizes[0] / 128;
  const int E = in_sizes[4];

  float* out   = (float*)d_out;
  float* a_out = out + (size_t)N*128;

  char* w = (char*)d_ws;
  unsigned short* hf16 = (unsigned short*)w; w += (size_t)N*128*sizeof(unsigned short);
  float* el      = (float*)w; w += (size_t)N*4*sizeof(float);
  float* er      = (float*)w; w += (size_t)N*4*sizeof(float);
  int2*  epack   = (int2*)w;  w += (size_t)E*sizeof(int2);
  int*   counts  = (int*)w;   w += (size_t)N*sizeof(int);
  int*   offsets = (int*)w;   w += (size_t)N*sizeof(int);
  int*   cursor  = (int*)w;   w += (size_t)N*sizeof(int);

  hipMemsetAsync(counts, 0, (size_t)N*sizeof(int), stream);

  k_proj<<<(N + 63)/64, 256, 0, stream>>>(h, fcw, attn_l, attn_r, hf16, el, er, N);

  int eth = (E + 3)/4;
  int ebl = (eth + 255)/256;
  k_hist<<<ebl, 256, 0, stream>>>(dst, counts, E);
  k_scan<<<1, 1024, 0, stream>>>(counts, N, offsets, cursor);
  k_scatter<<<ebl, 256, 0, stream>>>(dst, src, cursor, epack, E);

  k_aggr<<<(N + 3)/4, 256, 0, stream>>>(epack, offsets, counts, hf16, el, er, out, a_out, N);
}

// Round 4
// 210.987 us; speedup vs baseline: 1.5058x; 1.5058x over previous
//
#include <hip/hip_runtime.h>
#include <hip/hip_bf16.h>

#define NEG 0.2f

__device__ __forceinline__ float leaky(float x){ return x > 0.f ? x : NEG*x; }
__device__ __forceinline__ float sel4(float4 q, int head){
  float lo = (head & 1) ? q.y : q.x;
  float hi = (head & 1) ? q.w : q.z;
  return (head & 2) ? hi : lo;
}
__device__ __forceinline__ float b2f_lo(unsigned u){ return __uint_as_float(u << 16); }
__device__ __forceinline__ float b2f_hi(unsigned u){ return __uint_as_float(u & 0xffff0000u); }
__device__ __forceinline__ unsigned short f2b(float f){
  __hip_bfloat16 b = __float2bfloat16(f);
  return *(unsigned short*)&b;
}

// ---------------- K1: hf16 = bf16(h @ fcw^T), fused el/er. h read ONCE. ----------------
// grid.x = ceil(N/64). 256 threads. Both 64-feat halves computed per block.
__global__ __launch_bounds__(256) void k_proj(
    const float* __restrict__ h, const float* __restrict__ fcw,
    const float* __restrict__ attn_l, const float* __restrict__ attn_r,
    unsigned short* __restrict__ hf16, float* __restrict__ el, float* __restrict__ er, int N)
{
  __shared__ float fcs[64][128];
  __shared__ float hs[4][16][128];
  const int tid = threadIdx.x;
  const int wave = tid >> 6, lane = tid & 63;
  const int fq = lane & 15, ng = lane >> 4;
  const int nb0 = blockIdx.x*64 + wave*16;

  // stage this wave's 16 h rows (once)
  for (int t = lane; t < 16*32; t += 64) {
    int n = t >> 5, c = t & 31;
    int gn = nb0 + n; if (gn >= N) gn = N-1;
    *(float4*)&hs[wave][n][4*c] = *(const float4*)&h[(size_t)gn*128 + 4*c];
  }

  for (int g = 0; g < 2; ++g) {
    if (g) __syncthreads();           // protect fcs before restage
    // stage fc rows g*64 .. g*64+63, swizzle k-quads by (row>>2)&7
    for (int i = tid; i < 64*32; i += 256) {
      int f = i >> 5, q = i & 31;
      float4 w = *(const float4*)&fcw[(size_t)(g*64 + f)*128 + 4*q];
      *(float4*)&fcs[f][4*(q ^ ((f>>2)&7))] = w;
    }
    __syncthreads();

    float acc[4][4];
    #pragma unroll
    for (int j = 0; j < 4; ++j)
      #pragma unroll
      for (int i = 0; i < 4; ++i) acc[j][i] = 0.f;

    #pragma unroll 8
    for (int kk = 0; kk < 32; ++kk) {
      const int qc = 4*(kk ^ (fq & 7));
      float4 r0 = *(const float4*)&fcs[4*fq + 0][qc];
      float4 r1 = *(const float4*)&fcs[4*fq + 1][qc];
      float4 r2 = *(const float4*)&fcs[4*fq + 2][qc];
      float4 r3 = *(const float4*)&fcs[4*fq + 3][qc];
      #pragma unroll
      for (int j = 0; j < 4; ++j) {
        float4 hv = *(const float4*)&hs[wave][ng*4 + j][4*kk];
        acc[j][0] += hv.x*r0.x + hv.y*r0.y + hv.z*r0.z + hv.w*r0.w;
        acc[j][1] += hv.x*r1.x + hv.y*r1.y + hv.z*r1.z + hv.w*r1.w;
        acc[j][2] += hv.x*r2.x + hv.y*r2.y + hv.z*r2.z + hv.w*r2.w;
        acc[j][3] += hv.x*r3.x + hv.y*r3.y + hv.z*r3.z + hv.w*r3.w;
      }
    }

    const float4 al4 = *(const float4*)&attn_l[g*64 + 4*fq];
    const float4 ar4 = *(const float4*)&attn_r[g*64 + 4*fq];
    #pragma unroll
    for (int j = 0; j < 4; ++j) {
      int gn = nb0 + ng*4 + j;
      float4 o = make_float4(acc[j][0], acc[j][1], acc[j][2], acc[j][3]);
      float elp = o.x*al4.x + o.y*al4.y + o.z*al4.z + o.w*al4.w;
      float erp = o.x*ar4.x + o.y*ar4.y + o.z*ar4.z + o.w*ar4.w;
      elp += __shfl_xor(elp, 1); elp += __shfl_xor(elp, 2); elp += __shfl_xor(elp, 4);
      erp += __shfl_xor(erp, 1); erp += __shfl_xor(erp, 2); erp += __shfl_xor(erp, 4);
      if (gn < N) {
        ushort4 ob;
        ob.x = f2b(o.x); ob.y = f2b(o.y); ob.z = f2b(o.z); ob.w = f2b(o.w);
        *(ushort4*)&hf16[(size_t)gn*128 + g*64 + 4*fq] = ob;
        if ((lane & 7) == 0) {
          int head = g*2 + ((lane >> 3) & 1);
          el[(size_t)gn*4 + head] = elp;
          er[(size_t)gn*4 + head] = erp;
        }
      }
    }
  }
}

// ---------------- CSR build ----------------
__global__ void k_hist(const int* __restrict__ dst, int* __restrict__ counts, int E) {
  int e = (blockIdx.x*256 + threadIdx.x)*4;
  if (e + 3 < E) {
    int4 d = *(const int4*)&dst[e];
    atomicAdd(&counts[d.x], 1); atomicAdd(&counts[d.y], 1);
    atomicAdd(&counts[d.z], 1); atomicAdd(&counts[d.w], 1);
  } else {
    for (int k = e; k < E; ++k) atomicAdd(&counts[dst[k]], 1);
  }
}

__global__ __launch_bounds__(256) void k_block_sums(const int* __restrict__ counts, int N, int* __restrict__ bsum) {
  __shared__ int tmp[256];
  int i = blockIdx.x*256 + threadIdx.x;
  tmp[threadIdx.x] = (i < N) ? counts[i] : 0;
  __syncthreads();
  for (int off = 128; off > 0; off >>= 1) {
    if (threadIdx.x < off) tmp[threadIdx.x] += tmp[threadIdx.x + off];
    __syncthreads();
  }
  if (threadIdx.x == 0) bsum[blockIdx.x] = tmp[0];
}

__global__ __launch_bounds__(256) void k_scan_partials(int* __restrict__ bsum, int nb) {
  __shared__ int tmp[256];
  int t = threadIdx.x;
  int v = (t < nb) ? bsum[t] : 0;
  tmp[t] = v;
  __syncthreads();
  for (int off = 1; off < 256; off <<= 1) {
    int x = (t >= off) ? tmp[t - off] : 0;
    __syncthreads();
    tmp[t] += x;
    __syncthreads();
  }
  if (t < nb) bsum[t] = tmp[t] - v;   // exclusive prefix of block sums
}

__global__ __launch_bounds__(256) void k_scan_chunks(const int* __restrict__ counts, int N,
    const int* __restrict__ bsum, int* __restrict__ offsets, int* __restrict__ cursor) {
  __shared__ int tmp[256];
  int t = threadIdx.x;
  int i = blockIdx.x*256 + t;
  int v = (i < N) ? counts[i] : 0;
  tmp[t] = v;
  __syncthreads();
  for (int off = 1; off < 256; off <<= 1) {
    int x = (t >= off) ? tmp[t - off] : 0;
    __syncthreads();
    tmp[t] += x;
    __syncthreads();
  }
  if (i < N) {
    int excl = tmp[t] - v + bsum[blockIdx.x];
    offsets[i] = excl;
    cursor[i]  = excl;
  }
}

__global__ void k_scatter(const int* __restrict__ dst, const int* __restrict__ src,
                          int* __restrict__ cursor, int2* __restrict__ epack, int E) {
  int e = (blockIdx.x*256 + threadIdx.x)*4;
  if (e + 3 < E) {
    int4 d = *(const int4*)&dst[e];
    int4 s = *(const int4*)&src[e];
    int p0 = atomicAdd(&cursor[d.x], 1); epack[p0] = make_int2(e+0, s.x);
    int p1 = atomicAdd(&cursor[d.y], 1); epack[p1] = make_int2(e+1, s.y);
    int p2 = atomicAdd(&cursor[d.z], 1); epack[p2] = make_int2(e+2, s.z);
    int p3 = atomicAdd(&cursor[d.w], 1); epack[p3] = make_int2(e+3, s.w);
  } else {
    for (int k = e; k < E; ++k) {
      int d = dst[k];
      int p = atomicAdd(&cursor[d], 1);
      epack[p] = make_int2(k, src[k]);
    }
  }
}

// ---------------- K2: per-dst softmax + aggregation (1 wave per node) ----------------
// pass A (lane-per-edge, deg<=64 fast path): compute max/sum, write a_out,
//   stash a and (e,src) in LDS.
// pass B: 8 edge groups x 8 lanes, lane owns 16 feats (bf16 hf gather).
__global__ __launch_bounds__(256) void k_aggr(
    const int2* __restrict__ epack, const int* __restrict__ offsets, const int* __restrict__ counts,
    const unsigned short* __restrict__ hf16, const float* __restrict__ el, const float* __restrict__ er,
    float* __restrict__ out, float* __restrict__ a_out, int N)
{
  __shared__ float as[4][64][4];
  __shared__ int2  es[4][64];
  const int wave = threadIdx.x >> 6, lane = threadIdx.x & 63;
  const int v = blockIdx.x*4 + wave;
  if (v >= N) return;
  const int start = offsets[v];
  const int deg   = counts[v];
  const float4 er4 = *(const float4*)&er[(size_t)v*4];

  // ---- pass A ----
  const bool act = lane < deg;
  float4 e4 = make_float4(-1e30f, -1e30f, -1e30f, -1e30f);
  int2 myp = make_int2(0, 0);
  if (act) {
    myp = epack[start + lane];
    float4 el4 = *(const float4*)&el[(size_t)myp.y*4];
    e4.x = leaky(el4.x + er4.x);
    e4.y = leaky(el4.y + er4.y);
    e4.z = leaky(el4.z + er4.z);
    e4.w = leaky(el4.w + er4.w);
  }
  float4 m4 = e4;
  for (int j = lane + 64; j < deg; j += 64) {   // deg>64: essentially never
    int2 pr = epack[start + j];
    float4 el4 = *(const float4*)&el[(size_t)pr.y*4];
    m4.x = fmaxf(m4.x, leaky(el4.x + er4.x));
    m4.y = fmaxf(m4.y, leaky(el4.y + er4.y));
    m4.z = fmaxf(m4.z, leaky(el4.z + er4.z));
    m4.w = fmaxf(m4.w, leaky(el4.w + er4.w));
  }
  #pragma unroll
  for (int mm = 32; mm; mm >>= 1) {
    m4.x = fmaxf(m4.x, __shfl_xor(m4.x, mm));
    m4.y = fmaxf(m4.y, __shfl_xor(m4.y, mm));
    m4.z = fmaxf(m4.z, __shfl_xor(m4.z, mm));
    m4.w = fmaxf(m4.w, __shfl_xor(m4.w, mm));
  }
  float4 x4 = make_float4(0.f, 0.f, 0.f, 0.f);
  if (act) {
    x4.x = __expf(e4.x - m4.x);
    x4.y = __expf(e4.y - m4.y);
    x4.z = __expf(e4.z - m4.z);
    x4.w = __expf(e4.w - m4.w);
  }
  float4 s4 = x4;
  for (int j = lane + 64; j < deg; j += 64) {   // rare
    int2 pr = epack[start + j];
    float4 el4 = *(const float4*)&el[(size_t)pr.y*4];
    s4.x += __expf(leaky(el4.x + er4.x) - m4.x);
    s4.y += __expf(leaky(el4.y + er4.y) - m4.y);
    s4.z += __expf(leaky(el4.z + er4.z) - m4.z);
    s4.w += __expf(leaky(el4.w + er4.w) - m4.w);
  }
  #pragma unroll
  for (int mm = 32; mm; mm >>= 1) {
    s4.x += __shfl_xor(s4.x, mm);
    s4.y += __shfl_xor(s4.y, mm);
    s4.z += __shfl_xor(s4.z, mm);
    s4.w += __shfl_xor(s4.w, mm);
  }
  const float4 r4 = make_float4(1.f/s4.x, 1.f/s4.y, 1.f/s4.z, 1.f/s4.w);

  if (act) {
    float4 a4 = make_float4(x4.x*r4.x, x4.y*r4.y, x4.z*r4.z, x4.w*r4.w);
    *(float4*)&a_out[(size_t)myp.x*4] = a4;
    *(float4*)&as[wave][lane][0] = a4;
    es[wave][lane] = myp;
  }
  for (int j = lane + 64; j < deg; j += 64) {   // rare: a_out for spill edges
    int2 pr = epack[start + j];
    float4 el4 = *(const float4*)&el[(size_t)pr.y*4];
    float4 a4;
    a4.x = __expf(leaky(el4.x + er4.x) - m4.x) * r4.x;
    a4.y = __expf(leaky(el4.y + er4.y) - m4.y) * r4.y;
    a4.z = __expf(leaky(el4.z + er4.z) - m4.z) * r4.z;
    a4.w = __expf(leaky(el4.w + er4.w) - m4.w) * r4.w;
    *(float4*)&a_out[(size_t)pr.x*4] = a4;
  }

  // ---- pass B: aggregate, 8 edges in flight ----
  const int g = lane >> 3;      // edge slot 0..7
  const int l = lane & 7;       // feature sublane: feats 16l..16l+15
  const int head = l >> 1;
  float acc[16];
  #pragma unroll
  for (int k = 0; k < 16; ++k) acc[k] = 0.f;

  const int degL = deg < 64 ? deg : 64;
  for (int j = 0; j < degL; j += 8) {
    const int je = j + g;
    const bool valid = je < degL;
    const int jec = valid ? je : 0;
    int2 pr = es[wave][jec];
    float a = valid ? as[wave][jec][head] : 0.f;
    const unsigned short* hp = &hf16[(size_t)pr.y*128 + 16*l];
    uint4 q0 = *(const uint4*)hp;
    uint4 q1 = *(const uint4*)(hp + 8);
    acc[0]  += a*b2f_lo(q0.x); acc[1]  += a*b2f_hi(q0.x);
    acc[2]  += a*b2f_lo(q0.y); acc[3]  += a*b2f_hi(q0.y);
    acc[4]  += a*b2f_lo(q0.z); acc[5]  += a*b2f_hi(q0.z);
    acc[6]  += a*b2f_lo(q0.w); acc[7]  += a*b2f_hi(q0.w);
    acc[8]  += a*b2f_lo(q1.x); acc[9]  += a*b2f_hi(q1.x);
    acc[10] += a*b2f_lo(q1.y); acc[11] += a*b2f_hi(q1.y);
    acc[12] += a*b2f_lo(q1.z); acc[13] += a*b2f_hi(q1.z);
    acc[14] += a*b2f_lo(q1.w); acc[15] += a*b2f_hi(q1.w);
  }
  for (int j = 64; j < deg; j += 8) {   // deg>64 fallback: recompute a
    const int je = j + g;
    const bool valid = je < deg;
    int2 pr = epack[start + (valid ? je : 0)];
    float mh  = sel4(m4, head), rh = sel4(r4, head), erh = sel4(er4, head);
    float a = __expf(leaky(el[(size_t)pr.y*4 + head] + erh) - mh) * rh;
    if (!valid) a = 0.f;
    const unsigned short* hp = &hf16[(size_t)pr.y*128 + 16*l];
    uint4 q0 = *(const uint4*)hp;
    uint4 q1 = *(const uint4*)(hp + 8);
    acc[0]  += a*b2f_lo(q0.x); acc[1]  += a*b2f_hi(q0.x);
    acc[2]  += a*b2f_lo(q0.y); acc[3]  += a*b2f_hi(q0.y);
    acc[4]  += a*b2f_lo(q0.z); acc[5]  += a*b2f_hi(q0.z);
    acc[6]  += a*b2f_lo(q0.w); acc[7]  += a*b2f_hi(q0.w);
    acc[8]  += a*b2f_lo(q1.x); acc[9]  += a*b2f_hi(q1.x);
    acc[10] += a*b2f_lo(q1.y); acc[11] += a*b2f_hi(q1.y);
    acc[12] += a*b2f_lo(q1.z); acc[13] += a*b2f_hi(q1.z);
    acc[14] += a*b2f_lo(q1.w); acc[15] += a*b2f_hi(q1.w);
  }

  #pragma unroll
  for (int k = 0; k < 16; ++k) {
    acc[k] += __shfl_xor(acc[k], 8);
    acc[k] += __shfl_xor(acc[k], 16);
    acc[k] += __shfl_xor(acc[k], 32);
  }
  if (g == 0) {
    float* op = &out[(size_t)v*128 + 16*l];
    *(float4*)(op)      = make_float4(acc[0],  acc[1],  acc[2],  acc[3]);
    *(float4*)(op + 4)  = make_float4(acc[4],  acc[5],  acc[6],  acc[7]);
    *(float4*)(op + 8)  = make_float4(acc[8],  acc[9],  acc[10], acc[11]);
    *(float4*)(op + 12) = make_float4(acc[12], acc[13], acc[14], acc[15]);
  }
}

extern "C" void kernel_launch(void* const* d_in, const int* in_sizes, int n_in,
                              void* d_out, int out_size, void* d_ws, size_t ws_size,
                              hipStream_t stream) {
  const float* h      = (const float*)d_in[0];
  const float* fcw    = (const float*)d_in[1];
  const float* attn_l = (const float*)d_in[2];
  const float* attn_r = (const float*)d_in[3];
  const int*   src    = (const int*)d_in[4];
  const int*   dst    = (const int*)d_in[5];
  const int N = in_sizes[0] / 128;
  const int E = in_sizes[4];

  float* out   = (float*)d_out;
  float* a_out = out + (size_t)N*128;

  char* w = (char*)d_ws;
  unsigned short* hf16 = (unsigned short*)w; w += (size_t)N*128*sizeof(unsigned short);
  float* el      = (float*)w; w += (size_t)N*4*sizeof(float);
  float* er      = (float*)w; w += (size_t)N*4*sizeof(float);
  int2*  epack   = (int2*)w;  w += (size_t)E*sizeof(int2);
  int*   counts  = (int*)w;   w += (size_t)N*sizeof(int);
  int*   offsets = (int*)w;   w += (size_t)N*sizeof(int);
  int*   cursor  = (int*)w;   w += (size_t)N*sizeof(int);
  int*   bsum    = (int*)w;   w += 256*sizeof(int);

  hipMemsetAsync(counts, 0, (size_t)N*sizeof(int), stream);

  k_proj<<<(N + 63)/64, 256, 0, stream>>>(h, fcw, attn_l, attn_r, hf16, el, er, N);

  int eth = (E + 3)/4;
  int ebl = (eth + 255)/256;
  k_hist<<<ebl, 256, 0, stream>>>(dst, counts, E);

  int NB = (N + 255)/256;
  k_block_sums<<<NB, 256, 0, stream>>>(counts, N, bsum);
  k_scan_partials<<<1, 256, 0, stream>>>(bsum, NB);
  k_scan_chunks<<<NB, 256, 0, stream>>>(counts, N, bsum, offsets, cursor);

  k_scatter<<<ebl, 256, 0, stream>>>(dst, src, cursor, epack, E);

  k_aggr<<<(N + 3)/4, 256, 0, stream>>>(epack, offsets, counts, hf16, el, er, out, a_out, N);
}